// Round 5
// baseline (254.865 us; speedup 1.0000x reference)
//
#include <hip/hip_runtime.h>

#define N_NODES 50000
#define N_EDGES 800000
#define D 128
#define NW (N_NODES / 2)    // 25000 node pairs (int2 reads)
#define NWB 98              // ceil(NW/256) hist/scan blocks (512 nodes each)
#define NBLK 1563           // ceil(N_NODES/32) fused gather+gemm blocks
#define DUMMY 50000         // zero-row index for CSR padding
#define PSB 3125            // k_prescale main blocks (N*16/256)
#define EDGE_BLK 3125       // one edge per thread (x256)

typedef __attribute__((ext_vector_type(8))) short short8;   // 8 bf16
typedef __attribute__((ext_vector_type(4))) float f32x4;

__device__ __forceinline__ unsigned short f2bf(float f) {
    unsigned u = __float_as_uint(f);
    return (unsigned short)((u + 0x7FFFu + ((u >> 16) & 1u)) >> 16);  // RNE
}
__device__ __forceinline__ float bf2f(unsigned short h) {
    return __uint_as_float((unsigned)h << 16);
}

// accumulate 16 bf16 (packed in two uint4) into 16 f32
__device__ __forceinline__ void acc16(float* a, uint4 v0, uint4 v1) {
    unsigned w0 = v0.x, w1 = v0.y, w2 = v0.z, w3 = v0.w;
    unsigned w4 = v1.x, w5 = v1.y, w6 = v1.z, w7 = v1.w;
    a[0]  += __uint_as_float(w0 << 16);  a[1]  += __uint_as_float(w0 & 0xFFFF0000u);
    a[2]  += __uint_as_float(w1 << 16);  a[3]  += __uint_as_float(w1 & 0xFFFF0000u);
    a[4]  += __uint_as_float(w2 << 16);  a[5]  += __uint_as_float(w2 & 0xFFFF0000u);
    a[6]  += __uint_as_float(w3 << 16);  a[7]  += __uint_as_float(w3 & 0xFFFF0000u);
    a[8]  += __uint_as_float(w4 << 16);  a[9]  += __uint_as_float(w4 & 0xFFFF0000u);
    a[10] += __uint_as_float(w5 << 16);  a[11] += __uint_as_float(w5 & 0xFFFF0000u);
    a[12] += __uint_as_float(w6 << 16);  a[13] += __uint_as_float(w6 & 0xFFFF0000u);
    a[14] += __uint_as_float(w7 << 16);  a[15] += __uint_as_float(w7 & 0xFFFF0000u);
}

// ---- zero deg_in|deg_out (adjacent, 100000 ints = 25000 int4) ----
__global__ __launch_bounds__(256) void k_zero(int4* __restrict__ p) {
    int i = blockIdx.x * 256 + threadIdx.x;
    if (i < 2 * N_NODES / 4) p[i] = make_int4(0, 0, 0, 0);
}

// ---- degrees via global non-returning atomics (16 avg contention/addr) ----
__global__ __launch_bounds__(256) void k_deg(const int2* __restrict__ el2,
                                             int* __restrict__ deg_in,
                                             int* __restrict__ deg_out) {
    int i = blockIdx.x * 256 + threadIdx.x;
    if (i < N_EDGES) {
        int2 st = el2[i];
        atomicAdd(&deg_in[st.x], 1);
        atomicAdd(&deg_out[st.y], 1);
    }
}

// ---- per-512-node block: padded block sums + degree histogram dhistT[deg][blk] ----
__global__ __launch_bounds__(256) void k_hist2(const int* __restrict__ deg_out,
                                               int* __restrict__ blk_sum,
                                               int* __restrict__ dhistT) {
    __shared__ int sc[256];
    __shared__ int hb[256];
    int t = threadIdx.x;
    hb[t] = 0;
    int w = blockIdx.x * 256 + t;
    int v0 = 0, v1 = 0;
    if (w < NW) { int2 d2 = *(const int2*)&deg_out[2 * w]; v0 = d2.x; v1 = d2.y; }
    __syncthreads();  // hb zeroed and visible
    if (w < NW) {
        atomicAdd(&hb[v0 < 255 ? v0 : 255], 1);   // LDS atomics only
        atomicAdd(&hb[v1 < 255 ? v1 : 255], 1);
    }
    // padded row sizes (CSR rows rounded to multiple of 4 for ushort4 loads)
    sc[t] = (w < NW) ? (((v0 + 3) & ~3) + ((v1 + 3) & ~3)) : 0;
    __syncthreads();  // also orders the hb atomics above
    for (int s = 128; s > 0; s >>= 1) {
        if (t < s) sc[t] += sc[t + s];
        __syncthreads();
    }
    if (t == 0) blk_sum[blockIdx.x] = sc[0];
    dhistT[t * NWB + blockIdx.x] = hb[t];
}

// exclusive scan of the NWB (padded) block sums + exclusive scan of the
// (deg DESC, blk) bins into absolute base offsets dcur[deg][blk] (single block)
__global__ void k_scan_b(const int* __restrict__ blk_sum, int* __restrict__ blk_off,
                         const int* __restrict__ dhistT, int* __restrict__ dcur) {
    __shared__ int sc[256];
    int t = threadIdx.x;
    int v = (t < NWB) ? blk_sum[t] : 0;
    sc[t] = v;
    __syncthreads();
    for (int off = 1; off < 256; off <<= 1) {
        int a = (t >= off) ? sc[t - off] : 0;
        __syncthreads();
        sc[t] += a;
        __syncthreads();
    }
    if (t < NWB) blk_off[t] = sc[t] - v;  // exclusive
    __syncthreads();
    // thread t owns degree d=t; rows of dhistT are contiguous (NWB ints)
    int s = 0;
    #pragma unroll
    for (int i = 0; i < NWB; ++i) s += dhistT[t * NWB + i];
    sc[255 - t] = s;  // descending-degree order: slot u = 255-d
    __syncthreads();
    for (int off = 1; off < 256; off <<= 1) {
        int a = (t >= off) ? sc[t - off] : 0;
        __syncthreads();
        sc[t] += a;
        __syncthreads();
    }
    int run = sc[255 - t] - s;  // exclusive prefix for degree t (descending layout)
    #pragma unroll
    for (int i = 0; i < NWB; ++i) {
        int c = dhistT[t * NWB + i];
        dcur[t * NWB + i] = run;
        run += c;
    }
}

// row_start (PADDED) over 512 nodes/block + deterministic degree-sort placement
// + CSR pad-slot fill (DUMMY -> zero row) + cursor init (cur = row_start) for
// the atomic fill. order[] is DESCENDING degree (heavy blocks launch first).
__global__ void k_scan_c(const int* __restrict__ deg_out, const int* __restrict__ blk_off,
                         int* __restrict__ row_start, const int* __restrict__ dcur,
                         int* __restrict__ order, unsigned short* __restrict__ srcs,
                         int* __restrict__ cur) {
    __shared__ int sc[256];
    __shared__ int lcnt[256];
    int t = threadIdx.x;
    lcnt[t] = 0;
    int w = blockIdx.x * 256 + t;
    int v0 = 0, v1 = 0;
    if (w < NW) { int2 d2 = *(const int2*)&deg_out[2 * w]; v0 = d2.x; v1 = d2.y; }
    int ps0 = (v0 + 3) & ~3, ps1 = (v1 + 3) & ~3;
    int pair = ps0 + ps1;
    sc[t] = pair;
    __syncthreads();  // also makes lcnt zeroing visible
    for (int off = 1; off < 256; off <<= 1) {
        int a = (t >= off) ? sc[t - off] : 0;
        __syncthreads();
        sc[t] += a;
        __syncthreads();
    }
    if (w < NW) {
        int base = blk_off[blockIdx.x] + sc[t] - pair;
        *(int2*)&row_start[2 * w] = make_int2(base, base + ps0);
        *(int2*)&cur[2 * w]       = make_int2(base, base + ps0);
        for (int j = v0; j < ps0; ++j) srcs[base + j] = DUMMY;
        for (int j = v1; j < ps1; ++j) srcs[base + ps0 + j] = DUMMY;
        int d0 = v0 < 255 ? v0 : 255, d1 = v1 < 255 ? v1 : 255;
        int r0 = atomicAdd(&lcnt[d0], 1);  // LDS atomics only
        int r1 = atomicAdd(&lcnt[d1], 1);
        order[dcur[d0 * NWB + blockIdx.x] + r0] = 2 * w;
        order[dcur[d1 * NWB + blockIdx.x] + r1] = 2 * w + 1;
    }
}

// ---- CSR fill via returning global atomics on per-node cursors.
// 16 avg / ~45 max contention per address over 50K addresses (NOT the R1
// regime of 208-deep chains on 240 addresses). Within-row order arbitrary —
// sum is order-independent within tolerance. ----
__global__ __launch_bounds__(256) void k_fill2(const int2* __restrict__ el2,
                                               int* __restrict__ cur,
                                               unsigned short* __restrict__ srcs) {
    int i = blockIdx.x * 256 + threadIdx.x;
    if (i < N_EDGES) {
        int2 st = el2[i];
        int r = atomicAdd(&cur[st.y], 1);
        srcs[r] = (unsigned short)st.x;
    }
}

// ---- xst[n][128] = bf16(rsqrt(deg_in[n]+1) * x[n][:]) — row-contiguous 256B rows.
// Extra blocks: W -> bf16 (global Wb, read directly by k_gg) + zero DUMMY row. ----
__global__ void k_prescale(const float4* __restrict__ x4, const int* __restrict__ deg_in,
                           uint4* __restrict__ xst, const float4* __restrict__ W4,
                           ushort4* __restrict__ Wb4) {
    int b = blockIdx.x, t = threadIdx.x;
    if (b >= PSB) {
        int wi = b - PSB;
        if (wi < 16) {  // W: 16384 floats = 4096 float4, 16 blocks x 256 thr
            int idx = wi * 256 + t;
            float4 f = W4[idx];
            ushort4 h;
            h.x = f2bf(f.x); h.y = f2bf(f.y); h.z = f2bf(f.z); h.w = f2bf(f.w);
            Wb4[idx] = h;
        } else if (t < 16) {  // zero the DUMMY xst row (256 B)
            xst[(size_t)DUMMY * 16 + t] = make_uint4(0, 0, 0, 0);
        }
        return;
    }
    int g = b * 256 + t;  // N*16 groups of 8 elems
    int n = g >> 4, part = g & 15;
    float rs = rsqrtf((float)(deg_in[n] + 1));
    float4 a = x4[g * 2], c = x4[g * 2 + 1];
    uint4 o;
    o.x = f2bf(rs * a.x) | ((unsigned)f2bf(rs * a.y) << 16);
    o.y = f2bf(rs * a.z) | ((unsigned)f2bf(rs * a.w) << 16);
    o.z = f2bf(rs * c.x) | ((unsigned)f2bf(rs * c.y) << 16);
    o.w = f2bf(rs * c.z) | ((unsigned)f2bf(rs * c.w) << 16);
    xst[(size_t)n * 16 + part] = o;  // uint4 units (8 bf16)
}

// ---- fused gather + GEMM: per block 32 degree-sorted nodes (256 thr, 4 waves).
// Smaller blocks than R4 (512thr/64nodes): 1563 blocks = 6.1/CU residency vs
// 3.05 — finer drain granularity, more resident waves to hide gather latency.
// Snake mapping balances per-CU degree totals. B frags from global Wb (L2-hot).
// min-waves=4 keeps VGPR cap 128 (natural 48; =8 in R3 spilled: 120us lesson).
__global__ __launch_bounds__(256, 4) void k_gg(const unsigned short* __restrict__ Wb,
                                               const float* __restrict__ bias,
                                               const unsigned short* __restrict__ xst,
                                               const unsigned short* __restrict__ srcs,
                                               const int* __restrict__ row_start,
                                               const int* __restrict__ deg_out,
                                               const int* __restrict__ order,
                                               float* __restrict__ out) {
    __shared__ unsigned short As[32 * 136];   // 8.7 KB
    const int tid = threadIdx.x;

    // snake mapping: rounds of 256, odd rounds reversed
    int b = blockIdx.x;
    int r = b >> 8, pos = b & 255;
    int rbase = r << 8;
    int cntr = NBLK - rbase; if (cntr > 256) cntr = 256;
    int tile = (r & 1) ? (rbase + cntr - 1 - pos) : b;

    // ---- phase 1: gather ----
    const int slot = tid >> 3;            // As row 0..31
    const int d = tid & 7;                // 16-feature slice
    const int gslot = tile * 32 + slot;
    float acc[16];
    #pragma unroll
    for (int i = 0; i < 16; ++i) acc[i] = 0.f;

    if (gslot < N_NODES) {
        const int node = order[gslot];
        const int cnt = deg_out[node];
        const int cntp = (cnt + 3) & ~3;  // padded (pads -> DUMMY zero row)
        const uint4* xb = (const uint4*)xst;
        const int dof = d * 2;
        {   // self term (already rs-scaled)
            const uint4* xr = xb + (size_t)node * 16 + dof;
            acc16(acc, xr[0], xr[1]);
        }
        const unsigned short* p = srcs + row_start[node];  // 8B-aligned (rows %4)
        for (int k = 0; k < cntp; k += 4) {
            ushort4 s4 = *(const ushort4*)&p[k];
            const uint4* r0 = xb + (size_t)s4.x * 16 + dof;
            const uint4* r1 = xb + (size_t)s4.y * 16 + dof;
            const uint4* r2 = xb + (size_t)s4.z * 16 + dof;
            const uint4* r3 = xb + (size_t)s4.w * 16 + dof;
            uint4 a0 = r0[0], b0 = r0[1];
            uint4 a1 = r1[0], b1 = r1[1];
            uint4 a2 = r2[0], b2 = r2[1];
            uint4 a3 = r3[0], b3 = r3[1];
            acc16(acc, a0, b0); acc16(acc, a1, b1);
            acc16(acc, a2, b2); acc16(acc, a3, b3);
        }
        float rd = rsqrtf((float)(cnt + 1));
        #pragma unroll
        for (int i = 0; i < 16; ++i) acc[i] *= rd;
    }
    {   // pack 16 f32 -> 16 bf16 -> LDS (invalid slots write zeros; no early return!)
        unsigned wpk[8];
        #pragma unroll
        for (int i = 0; i < 8; ++i)
            wpk[i] = (unsigned)f2bf(acc[2 * i]) | ((unsigned)f2bf(acc[2 * i + 1]) << 16);
        uint4* dst = (uint4*)&As[slot * 136 + d * 16];
        dst[0] = make_uint4(wpk[0], wpk[1], wpk[2], wpk[3]);
        dst[1] = make_uint4(wpk[4], wpk[5], wpk[6], wpk[7]);
    }
    __syncthreads();

    // ---- phase 2: 32x128 GEMM, 4 waves = 2 row-tiles x 2 col-halves ----
    const int wv = tid >> 6, lane = tid & 63, ml = lane & 15, q = lane >> 4;
    const int rt = wv & 1, half = wv >> 1;
    const int arow = rt * 16 + ml;
    short8 a[4];
    #pragma unroll
    for (int kt = 0; kt < 4; ++kt)
        a[kt] = *(const short8*)&As[arow * 136 + kt * 32 + q * 8];

    f32x4 accm[4];
    #pragma unroll
    for (int jj = 0; jj < 4; ++jj) accm[jj] = (f32x4){0.f, 0.f, 0.f, 0.f};
    #pragma unroll
    for (int jj = 0; jj < 4; ++jj) {
        #pragma unroll
        for (int kt = 0; kt < 4; ++kt) {
            short8 bw = *(const short8*)&Wb[(half * 64 + jj * 16 + ml) * D + kt * 32 + q * 8];
            accm[jj] = __builtin_amdgcn_mfma_f32_16x16x32_bf16(a[kt], bw, accm[jj], 0, 0, 0);
        }
    }
    #pragma unroll
    for (int jj = 0; jj < 4; ++jj) {
        float bj = bias[half * 64 + jj * 16 + ml];
        #pragma unroll
        for (int r4 = 0; r4 < 4; ++r4) {
            int s = rt * 16 + q * 4 + r4;
            int gs = tile * 32 + s;
            if (gs < N_NODES) {
                int nd = order[gs];
                float v = accm[jj][r4] + bj;
                out[nd * D + half * 64 + jj * 16 + ml] = v > 0.f ? v : 0.f;
            }
        }
    }
}

extern "C" void kernel_launch(void* const* d_in, const int* in_sizes, int n_in,
                              void* d_out, int out_size, void* d_ws, size_t ws_size,
                              hipStream_t stream) {
    const int*   el = (const int*)d_in[0];
    const float* x  = (const float*)d_in[1];
    const float* W  = (const float*)d_in[2];
    const float* b  = (const float*)d_in[3];
    float* out = (float*)d_out;

    // workspace layout (~16 MB; partials/brel machinery deleted)
    unsigned short* xst  = (unsigned short*)d_ws;                            // (N+1)*128 bf16
    unsigned short* srcs = xst + (size_t)(N_NODES + 1) * D;                  // <=1M u16 (padded)
    int* deg_in    = (int*)(srcs + 1000000);                                 // N  (adjacent:
    int* deg_out   = deg_in + N_NODES;                                       //  N  zeroed together)
    int* row_start = deg_out + N_NODES;                                      // N
    int* cur       = row_start + N_NODES;                                    // N
    int* blk_sum   = cur + N_NODES;                                          // 256
    int* blk_off   = blk_sum + 256;                                          // 256
    int* dhistT    = blk_off + 256;                                          // 256*NWB = 25088
    int* dcur      = dhistT + 256 * NWB;                                     // 25088
    int* order     = dcur + 256 * NWB;                                       // N
    unsigned short* Wb = (unsigned short*)(order + N_NODES);                 // 128*128 bf16

    k_zero<<<98, 256, 0, stream>>>((int4*)deg_in);
    k_deg<<<EDGE_BLK, 256, 0, stream>>>((const int2*)el, deg_in, deg_out);
    k_hist2<<<NWB, 256, 0, stream>>>(deg_out, blk_sum, dhistT);
    k_scan_b<<<1, 256, 0, stream>>>(blk_sum, blk_off, dhistT, dcur);
    k_scan_c<<<NWB, 256, 0, stream>>>(deg_out, blk_off, row_start, dcur, order, srcs, cur);
    k_prescale<<<PSB + 17, 256, 0, stream>>>((const float4*)x, deg_in, (uint4*)xst,
                                             (const float4*)W, (ushort4*)Wb);
    k_fill2<<<EDGE_BLK, 256, 0, stream>>>((const int2*)el, cur, srcs);
    k_gg<<<NBLK, 256, 0, stream>>>(Wb, b, xst, srcs, row_start, deg_out, order, out);
}

// Round 6
// 185.977 us; speedup vs baseline: 1.3704x; 1.3704x over previous
//
#include <hip/hip_runtime.h>

#define N_NODES 50000
#define N_EDGES 800000
#define D 128
#define HP 128              // histogram / fill partition blocks
#define EPB (N_EDGES / HP)  // 6250 edges per partition
#define NW (N_NODES / 2)    // 25000 packed u32 words (2 nodes/word)
#define RNB 196             // ceil(N_NODES/256) reduce/scan blocks (256 nodes each)
#define NBLK 782            // ceil(N_NODES/64) fused gather+gemm blocks
#define DUMMY 50000         // zero-row index for CSR padding
#define PSB 3125            // k_prescale main blocks (N*16/256)

typedef __attribute__((ext_vector_type(8))) short short8;   // 8 bf16
typedef __attribute__((ext_vector_type(4))) float f32x4;

__device__ __forceinline__ unsigned short f2bf(float f) {
    unsigned u = __float_as_uint(f);
    return (unsigned short)((u + 0x7FFFu + ((u >> 16) & 1u)) >> 16);  // RNE
}
__device__ __forceinline__ float bf2f(unsigned short h) {
    return __uint_as_float((unsigned)h << 16);
}

// accumulate 16 bf16 (packed in two uint4) into 16 f32
__device__ __forceinline__ void acc16(float* a, uint4 v0, uint4 v1) {
    unsigned w0 = v0.x, w1 = v0.y, w2 = v0.z, w3 = v0.w;
    unsigned w4 = v1.x, w5 = v1.y, w6 = v1.z, w7 = v1.w;
    a[0]  += __uint_as_float(w0 << 16);  a[1]  += __uint_as_float(w0 & 0xFFFF0000u);
    a[2]  += __uint_as_float(w1 << 16);  a[3]  += __uint_as_float(w1 & 0xFFFF0000u);
    a[4]  += __uint_as_float(w2 << 16);  a[5]  += __uint_as_float(w2 & 0xFFFF0000u);
    a[6]  += __uint_as_float(w3 << 16);  a[7]  += __uint_as_float(w3 & 0xFFFF0000u);
    a[8]  += __uint_as_float(w4 << 16);  a[9]  += __uint_as_float(w4 & 0xFFFF0000u);
    a[10] += __uint_as_float(w5 << 16);  a[11] += __uint_as_float(w5 & 0xFFFF0000u);
    a[12] += __uint_as_float(w6 << 16);  a[13] += __uint_as_float(w6 & 0xFFFF0000u);
    a[14] += __uint_as_float(w7 << 16);  a[15] += __uint_as_float(w7 & 0xFFFF0000u);
}

// ---- degrees via per-block LDS histograms, 1024 threads (16 waves/block:
// the 256-thread version ran 1 block/CU = 1 wave/SIMD, pure latency-bound).
// LDS word w packs: in[2w](b0) | out[2w](b1) | in[2w+1](b2) | out[2w+1](b3), u8 each.
__global__ __launch_bounds__(1024) void k_hist(const int2* __restrict__ el2,
                                               unsigned int* __restrict__ partials) {
    __shared__ unsigned int h[NW];  // 100 KB
    int t = threadIdx.x;
    for (int i = t; i < NW / 4; i += 1024) ((uint4*)h)[i] = make_uint4(0, 0, 0, 0);
    __syncthreads();
    const int2* p = el2 + blockIdx.x * EPB;
    for (int i = t; i < EPB; i += 1024) {
        int2 st = p[i];
        atomicAdd(&h[st.x >> 1], 1u << ((st.x & 1) * 16));       // in-degree byte
        atomicAdd(&h[st.y >> 1], 256u << ((st.y & 1) * 16));     // out-degree byte
    }
    __syncthreads();
    uint4* dst = (uint4*)(partials + (size_t)blockIdx.x * NW);
    for (int i = t; i < NW / 4; i += 1024) dst[i] = ((uint4*)h)[i];
}

// ---- thread-per-node reduce: degree totals + per-partition exclusive prefix
// (brel, u8/node/partition) + padded block sums + degree histogram dhistT.
// Partials loads batched x8 (independent addresses -> one vmcnt wait per 8).
__global__ __launch_bounds__(256) void k_reduce(const unsigned int* __restrict__ partials,
                                                unsigned char* __restrict__ brel,
                                                int* __restrict__ deg_in,
                                                int* __restrict__ deg_out,
                                                int* __restrict__ blk_sum,
                                                int* __restrict__ dhistT) {
    __shared__ int sc[256];
    __shared__ int hb[256];
    int t = threadIdx.x;
    hb[t] = 0;
    int n = blockIdx.x * 256 + t;
    bool ok = n < N_NODES;
    int w = n >> 1, sh = (n & 1) * 16;
    int si = 0, so = 0;
    if (ok) {
        for (int p0 = 0; p0 < HP; p0 += 8) {
            unsigned v[8];
            #pragma unroll
            for (int j = 0; j < 8; ++j) v[j] = partials[(size_t)(p0 + j) * NW + w];
            #pragma unroll
            for (int j = 0; j < 8; ++j) {
                brel[(size_t)(p0 + j) * N_NODES + n] = (unsigned char)so;  // excl prefix
                si += (int)((v[j] >> sh) & 0xFFu);
                so += (int)((v[j] >> (sh + 8)) & 0xFFu);
            }
        }
        deg_in[n] = si;
        deg_out[n] = so;
    }
    __syncthreads();  // hb zeroed and visible
    if (ok) atomicAdd(&hb[so < 255 ? so : 255], 1);   // LDS atomics only
    // padded row size (CSR rows rounded to multiple of 4 for ushort4 loads)
    sc[t] = ok ? ((so + 3) & ~3) : 0;
    __syncthreads();  // also orders the hb atomics above
    for (int s = 128; s > 0; s >>= 1) {
        if (t < s) sc[t] += sc[t + s];
        __syncthreads();
    }
    if (t == 0) blk_sum[blockIdx.x] = sc[0];
    dhistT[t * RNB + blockIdx.x] = hb[t];   // transposed for k_scan_b
}

// exclusive scan of the RNB (padded) block sums + exclusive scan of the
// (deg DESC, blk) bins into absolute base offsets dcur[deg][blk] (single block)
__global__ void k_scan_b(const int* __restrict__ blk_sum, int* __restrict__ blk_off,
                         const int* __restrict__ dhistT, int* __restrict__ dcur) {
    __shared__ int sc[256];
    int t = threadIdx.x;
    int v = (t < RNB) ? blk_sum[t] : 0;
    sc[t] = v;
    __syncthreads();
    for (int off = 1; off < 256; off <<= 1) {
        int a = (t >= off) ? sc[t - off] : 0;
        __syncthreads();
        sc[t] += a;
        __syncthreads();
    }
    if (t < RNB) blk_off[t] = sc[t] - v;  // exclusive
    __syncthreads();
    // thread t owns degree d=t; rows of dhistT are contiguous (RNB ints)
    int s = 0;
    #pragma unroll
    for (int i = 0; i < RNB; ++i) s += dhistT[t * RNB + i];
    sc[255 - t] = s;  // descending-degree order: slot u = 255-d
    __syncthreads();
    for (int off = 1; off < 256; off <<= 1) {
        int a = (t >= off) ? sc[t - off] : 0;
        __syncthreads();
        sc[t] += a;
        __syncthreads();
    }
    int run = sc[255 - t] - s;  // exclusive prefix for degree t (descending layout)
    #pragma unroll
    for (int i = 0; i < RNB; ++i) {
        int c = dhistT[t * RNB + i];
        dcur[t * RNB + i] = run;
        run += c;
    }
}

// row_start (PADDED) thread-per-node + deterministic degree-sort placement
// + CSR pad-slot fill (DUMMY -> zero row). order[] is DESCENDING degree.
__global__ void k_scan_c(const int* __restrict__ deg_out, const int* __restrict__ blk_off,
                         int* __restrict__ row_start, const int* __restrict__ dcur,
                         int* __restrict__ order, unsigned short* __restrict__ srcs) {
    __shared__ int sc[256];
    __shared__ int lcnt[256];
    int t = threadIdx.x;
    lcnt[t] = 0;
    int n = blockIdx.x * 256 + t;
    int v = (n < N_NODES) ? deg_out[n] : 0;
    int ps = (v + 3) & ~3;
    sc[t] = ps;
    __syncthreads();  // also makes lcnt zeroing visible
    for (int off = 1; off < 256; off <<= 1) {
        int a = (t >= off) ? sc[t - off] : 0;
        __syncthreads();
        sc[t] += a;
        __syncthreads();
    }
    if (n < N_NODES) {
        int base = blk_off[blockIdx.x] + sc[t] - ps;
        row_start[n] = base;
        for (int j = v; j < ps; ++j) srcs[base + j] = DUMMY;
        int d = v < 255 ? v : 255;
        int r = atomicAdd(&lcnt[d], 1);  // LDS atomics only
        order[dcur[d * RNB + blockIdx.x] + r] = n;
    }
}

// ---- counting-sort placement, 1024 threads, NO global atomics ----
__global__ __launch_bounds__(1024) void k_fill(const int2* __restrict__ el2,
                                               const int* __restrict__ row_start,
                                               const unsigned char* __restrict__ brel,
                                               unsigned short* __restrict__ srcs) {
    __shared__ unsigned int cur[NW];  // 100 KB packed u16 cursors
    int t = threadIdx.x;
    for (int i = t; i < NW / 4; i += 1024) ((uint4*)cur)[i] = make_uint4(0, 0, 0, 0);
    __syncthreads();
    const int2* p = el2 + blockIdx.x * EPB;
    const unsigned char* br = brel + (size_t)blockIdx.x * N_NODES;
    for (int i = t; i < EPB; i += 1024) {
        int2 st = p[i];
        int n = st.y;
        unsigned old = atomicAdd(&cur[n >> 1], 1u << ((n & 1) * 16));
        int rank = (old >> ((n & 1) * 16)) & 0xFFFF;
        srcs[row_start[n] + (int)br[n] + rank] = (unsigned short)st.x;
    }
}

// ---- xst[n][128] = bf16(rsqrt(deg_in[n]+1) * x[n][:]) — row-contiguous 256B rows.
// Extra blocks: W -> bf16 (global Wb, staged to LDS by k_gg) + zero DUMMY row. ----
__global__ void k_prescale(const float4* __restrict__ x4, const int* __restrict__ deg_in,
                           uint4* __restrict__ xst, const float4* __restrict__ W4,
                           ushort4* __restrict__ Wb4) {
    int b = blockIdx.x, t = threadIdx.x;
    if (b >= PSB) {
        int wi = b - PSB;
        if (wi < 16) {  // W: 16384 floats = 4096 float4, 16 blocks x 256 thr
            int idx = wi * 256 + t;
            float4 f = W4[idx];
            ushort4 h;
            h.x = f2bf(f.x); h.y = f2bf(f.y); h.z = f2bf(f.z); h.w = f2bf(f.w);
            Wb4[idx] = h;
        } else if (t < 16) {  // zero the DUMMY xst row (256 B)
            xst[(size_t)DUMMY * 16 + t] = make_uint4(0, 0, 0, 0);
        }
        return;
    }
    int g = b * 256 + t;  // N*16 groups of 8 elems
    int n = g >> 4, part = g & 15;
    float rs = rsqrtf((float)(deg_in[n] + 1));
    float4 a = x4[g * 2], c = x4[g * 2 + 1];
    uint4 o;
    o.x = f2bf(rs * a.x) | ((unsigned)f2bf(rs * a.y) << 16);
    o.y = f2bf(rs * a.z) | ((unsigned)f2bf(rs * a.w) << 16);
    o.z = f2bf(rs * c.x) | ((unsigned)f2bf(rs * c.y) << 16);
    o.w = f2bf(rs * c.z) | ((unsigned)f2bf(rs * c.w) << 16);
    xst[(size_t)n * 16 + part] = o;  // uint4 units (8 bf16)
}

// ---- fused gather + GEMM: per block 64 degree-sorted nodes, 512 threads.
// W staged in LDS (R2's 45us config — global-Wb B-frags got evicted by the
// 87MB gather stream: R4's 50us). Snake mapping balances per-CU degree totals.
// Padded rows -> ushort4 index loads; next-chunk prefetch breaks the
// srcs->row dependency chain. min-waves=4 (VGPR cap 128; =8 spilled in R3).
__global__ __launch_bounds__(512, 4) void k_gg(const unsigned short* __restrict__ Wb,
                                               const float* __restrict__ bias,
                                               const unsigned short* __restrict__ xst,
                                               const unsigned short* __restrict__ srcs,
                                               const int* __restrict__ row_start,
                                               const int* __restrict__ deg_out,
                                               const int* __restrict__ order,
                                               float* __restrict__ out) {
    __shared__ unsigned short Wl[128 * 136];  // 34.8 KB
    __shared__ unsigned short As[64 * 136];   // 17.4 KB
    const int tid = threadIdx.x;

    // stage Wb (bf16, 32 KB) -> LDS once per block
    for (int i = tid; i < 2048; i += 512) {
        int r = i >> 4, c = i & 15;
        *(uint4*)&Wl[r * 136 + c * 8] = ((const uint4*)Wb)[i];
    }

    // snake mapping: rounds of 256, odd rounds reversed
    int b = blockIdx.x;
    int rr = b >> 8, pos = b & 255;
    int rbase = rr << 8;
    int cntr = NBLK - rbase; if (cntr > 256) cntr = 256;
    int tile = (rr & 1) ? (rbase + cntr - 1 - pos) : b;

    // ---- phase 1: gather ----
    const int slot = tid >> 3;            // As row 0..63
    const int d = tid & 7;                // 16-feature slice
    const int gslot = tile * 64 + slot;
    float acc[16];
    #pragma unroll
    for (int i = 0; i < 16; ++i) acc[i] = 0.f;

    if (gslot < N_NODES) {
        const int node = order[gslot];
        const int cnt = deg_out[node];
        const int cntp = (cnt + 3) & ~3;  // padded (pads -> DUMMY zero row)
        const uint4* xb = (const uint4*)xst;
        const int dof = d * 2;
        {   // self term (already rs-scaled)
            const uint4* xr = xb + (size_t)node * 16 + dof;
            acc16(acc, xr[0], xr[1]);
        }
        const unsigned short* p = srcs + row_start[node];  // 8B-aligned (rows %4)
        ushort4 s4 = *(const ushort4*)&p[0];  // may overread into ws: mapped, unused
        for (int k = 0; k < cntp; k += 4) {
            ushort4 nx = *(const ushort4*)&p[k + 4];  // prefetch next chunk
            const uint4* r0 = xb + (size_t)s4.x * 16 + dof;
            const uint4* r1 = xb + (size_t)s4.y * 16 + dof;
            const uint4* r2 = xb + (size_t)s4.z * 16 + dof;
            const uint4* r3 = xb + (size_t)s4.w * 16 + dof;
            uint4 a0 = r0[0], b0 = r0[1];
            uint4 a1 = r1[0], b1 = r1[1];
            uint4 a2 = r2[0], b2 = r2[1];
            uint4 a3 = r3[0], b3 = r3[1];
            acc16(acc, a0, b0); acc16(acc, a1, b1);
            acc16(acc, a2, b2); acc16(acc, a3, b3);
            s4 = nx;
        }
        float rd = rsqrtf((float)(cnt + 1));
        #pragma unroll
        for (int i = 0; i < 16; ++i) acc[i] *= rd;
    }
    {   // pack 16 f32 -> 16 bf16 -> LDS (invalid slots write zeros; no early return!)
        unsigned wpk[8];
        #pragma unroll
        for (int i = 0; i < 8; ++i)
            wpk[i] = (unsigned)f2bf(acc[2 * i]) | ((unsigned)f2bf(acc[2 * i + 1]) << 16);
        uint4* dst = (uint4*)&As[slot * 136 + d * 16];
        dst[0] = make_uint4(wpk[0], wpk[1], wpk[2], wpk[3]);
        dst[1] = make_uint4(wpk[4], wpk[5], wpk[6], wpk[7]);
    }
    __syncthreads();

    // ---- phase 2: 64x128 GEMM, 8 waves = 4 row-tiles x 2 col-halves ----
    const int wv = tid >> 6, lane = tid & 63, ml = lane & 15, q = lane >> 4;
    const int rt = wv & 3, half = wv >> 2;
    const int arow = rt * 16 + ml;
    short8 a[4];
    #pragma unroll
    for (int kt = 0; kt < 4; ++kt)
        a[kt] = *(const short8*)&As[arow * 136 + kt * 32 + q * 8];

    f32x4 accm[4];
    #pragma unroll
    for (int jj = 0; jj < 4; ++jj) accm[jj] = (f32x4){0.f, 0.f, 0.f, 0.f};
    #pragma unroll
    for (int jj = 0; jj < 4; ++jj) {
        #pragma unroll
        for (int kt = 0; kt < 4; ++kt) {
            short8 bw = *(const short8*)&Wl[(half * 64 + jj * 16 + ml) * 136 + kt * 32 + q * 8];
            accm[jj] = __builtin_amdgcn_mfma_f32_16x16x32_bf16(a[kt], bw, accm[jj], 0, 0, 0);
        }
    }
    #pragma unroll
    for (int jj = 0; jj < 4; ++jj) {
        float bj = bias[half * 64 + jj * 16 + ml];
        #pragma unroll
        for (int r4 = 0; r4 < 4; ++r4) {
            int s = rt * 16 + q * 4 + r4;
            int gs = tile * 64 + s;
            if (gs < N_NODES) {
                int nd = order[gs];
                float v = accm[jj][r4] + bj;
                out[nd * D + half * 64 + jj * 16 + ml] = v > 0.f ? v : 0.f;
            }
        }
    }
}

extern "C" void kernel_launch(void* const* d_in, const int* in_sizes, int n_in,
                              void* d_out, int out_size, void* d_ws, size_t ws_size,
                              hipStream_t stream) {
    const int*   el = (const int*)d_in[0];
    const float* x  = (const float*)d_in[1];
    const float* W  = (const float*)d_in[2];
    const float* b  = (const float*)d_in[3];
    float* out = (float*)d_out;

    // workspace layout (~29 MB)
    unsigned int* partials = (unsigned int*)d_ws;                            // HP*NW u32 = 12.8M
    unsigned short* xst    = (unsigned short*)(partials + (size_t)HP * NW);  // (N+1)*128 bf16
    unsigned char* brel    = (unsigned char*)(xst + (size_t)(N_NODES + 1) * D); // HP*N u8 = 6.4M
    unsigned short* srcs   = (unsigned short*)(brel + (size_t)HP * N_NODES); // <=1M u16 (padded)
    int* deg_in    = (int*)(srcs + 1000000);                                 // N
    int* deg_out   = deg_in + N_NODES;                                       // N
    int* row_start = deg_out + N_NODES;                                      // N
    int* blk_sum   = row_start + N_NODES;                                    // 256
    int* blk_off   = blk_sum + 256;                                          // 256
    int* dhistT    = blk_off + 256;                                          // 256*RNB = 50176
    int* dcur      = dhistT + 256 * RNB;                                     // 50176
    int* order     = dcur + 256 * RNB;                                       // N
    unsigned short* Wb = (unsigned short*)(order + N_NODES);                 // 128*128 bf16

    k_hist<<<HP, 1024, 0, stream>>>((const int2*)el, partials);
    k_reduce<<<RNB, 256, 0, stream>>>(partials, brel, deg_in, deg_out, blk_sum, dhistT);
    k_scan_b<<<1, 256, 0, stream>>>(blk_sum, blk_off, dhistT, dcur);
    k_scan_c<<<RNB, 256, 0, stream>>>(deg_out, blk_off, row_start, dcur, order, srcs);
    k_prescale<<<PSB + 17, 256, 0, stream>>>((const float4*)x, deg_in, (uint4*)xst,
                                             (const float4*)W, (ushort4*)Wb);
    k_fill<<<HP, 1024, 0, stream>>>((const int2*)el, row_start, brel, srcs);
    k_gg<<<NBLK, 512, 0, stream>>>(Wb, b, xst, srcs, row_start, deg_out, order, out);
}